// Round 1
// baseline (9752.754 us; speedup 1.0000x reference)
//
#include <hip/hip_runtime.h>
#include <math.h>

#define TPB 256

// ---------------------------------------------------------------------------
// subm: 3x3x3 SAME conv (+optional fused concat of two inputs) + BN + ReLU + mask
// thread = (voxel, co), co fastest -> coalesced weight reads / output writes
// ---------------------------------------------------------------------------
template<int C1, int C2, int Co>
__global__ void __launch_bounds__(TPB) k_subm(
    const float* __restrict__ x1, const float* __restrict__ x2,
    const float* __restrict__ wgt,   // (3,3,3,C1+C2,Co)
    const float* __restrict__ bn,    // (4,Co): gamma,beta,mean,var
    const float* __restrict__ mask,  // (D,H,W)
    float* __restrict__ out,         // (D,H,W,Co)
    int D, int H, int W)
{
  constexpr int Cin = C1 + C2;
  const int total = D * H * W * Co;
  for (int idx = blockIdx.x * TPB + threadIdx.x; idx < total; idx += gridDim.x * TPB) {
    const int co = idx % Co;
    const int v  = idx / Co;
    const int w = v % W;
    const int h = (v / W) % H;
    const int d = v / (W * H);
    float outv = 0.f;
    if (mask[v] != 0.f) {
      float a0 = 0.f, a1 = 0.f, a2 = 0.f, a3 = 0.f;
      for (int kd = 0; kd < 3; ++kd) { const int zd = d + kd - 1; if ((unsigned)zd >= (unsigned)D) continue;
      for (int kh = 0; kh < 3; ++kh) { const int zh = h + kh - 1; if ((unsigned)zh >= (unsigned)H) continue;
      for (int kw = 0; kw < 3; ++kw) { const int zw = w + kw - 1; if ((unsigned)zw >= (unsigned)W) continue;
        const int nv  = (zd * H + zh) * W + zw;
        const int tap = (kd * 3 + kh) * 3 + kw;
        const float* __restrict__ wp = wgt + tap * (Cin * Co) + co;
        const float* __restrict__ xp = x1 + nv * C1;
        #pragma unroll
        for (int ci = 0; ci < C1; ci += 4) {
          a0 = fmaf(xp[ci + 0], wp[(ci + 0) * Co], a0);
          a1 = fmaf(xp[ci + 1], wp[(ci + 1) * Co], a1);
          a2 = fmaf(xp[ci + 2], wp[(ci + 2) * Co], a2);
          a3 = fmaf(xp[ci + 3], wp[(ci + 3) * Co], a3);
        }
        if constexpr (C2 > 0) {
          const float* __restrict__ xq = x2 + nv * C2;
          const float* __restrict__ wq = wp + C1 * Co;
          #pragma unroll
          for (int ci = 0; ci < C2; ci += 4) {
            a0 = fmaf(xq[ci + 0], wq[(ci + 0) * Co], a0);
            a1 = fmaf(xq[ci + 1], wq[(ci + 1) * Co], a1);
            a2 = fmaf(xq[ci + 2], wq[(ci + 2) * Co], a2);
            a3 = fmaf(xq[ci + 3], wq[(ci + 3) * Co], a3);
          }
        }
      }}}
      float acc = (a0 + a1) + (a2 + a3);
      const float g  = bn[co];
      const float be = bn[Co + co];
      const float mu = bn[2 * Co + co];
      const float va = bn[3 * Co + co];
      acc  = (acc - mu) * (g * rsqrtf(va + 1e-5f)) + be;
      outv = fmaxf(acc, 0.f);
    }
    out[idx] = outv;
  }
}

// ---------------------------------------------------------------------------
// down: 2x2x2 stride-2 VALID conv + BN + ReLU + pooled mask (also writes mask)
// D,H,W are OUTPUT dims; input is (2D,2H,2W,Ci)
// ---------------------------------------------------------------------------
template<int Ci, int Co>
__global__ void __launch_bounds__(TPB) k_down(
    const float* __restrict__ x, const float* __restrict__ wgt,  // (2,2,2,Ci,Co)
    const float* __restrict__ bn, const float* __restrict__ mfine,
    float* __restrict__ mout, float* __restrict__ out,
    int D, int H, int W)
{
  const int total = D * H * W * Co;
  const int Hf = 2 * H, Wf = 2 * W;
  for (int idx = blockIdx.x * TPB + threadIdx.x; idx < total; idx += gridDim.x * TPB) {
    const int co = idx % Co;
    const int v  = idx / Co;
    const int w = v % W;
    const int h = (v / W) % H;
    const int d = v / (W * H);
    float mp = 0.f;
    #pragma unroll
    for (int dz = 0; dz < 2; ++dz)
      #pragma unroll
      for (int hz = 0; hz < 2; ++hz)
        #pragma unroll
        for (int wz = 0; wz < 2; ++wz)
          mp = fmaxf(mp, mfine[((2 * d + dz) * Hf + (2 * h + hz)) * Wf + (2 * w + wz)]);
    if (co == 0) mout[v] = mp;
    float outv = 0.f;
    if (mp != 0.f) {
      float a0 = 0.f, a1 = 0.f, a2 = 0.f, a3 = 0.f;
      #pragma unroll
      for (int kd = 0; kd < 2; ++kd)
        #pragma unroll
        for (int kh = 0; kh < 2; ++kh)
          #pragma unroll
          for (int kw = 0; kw < 2; ++kw) {
            const int nv  = ((2 * d + kd) * Hf + (2 * h + kh)) * Wf + (2 * w + kw);
            const int tap = (kd * 2 + kh) * 2 + kw;
            const float* __restrict__ wp = wgt + tap * (Ci * Co) + co;
            const float* __restrict__ xp = x + nv * Ci;
            #pragma unroll
            for (int ci = 0; ci < Ci; ci += 4) {
              a0 = fmaf(xp[ci + 0], wp[(ci + 0) * Co], a0);
              a1 = fmaf(xp[ci + 1], wp[(ci + 1) * Co], a1);
              a2 = fmaf(xp[ci + 2], wp[(ci + 2) * Co], a2);
              a3 = fmaf(xp[ci + 3], wp[(ci + 3) * Co], a3);
            }
          }
      float acc = (a0 + a1) + (a2 + a3);
      const float g  = bn[co];
      const float be = bn[Co + co];
      const float mu = bn[2 * Co + co];
      const float va = bn[3 * Co + co];
      acc  = (acc - mu) * (g * rsqrtf(va + 1e-5f)) + be;
      outv = fmaxf(acc, 0.f);
    }
    out[idx] = outv;
  }
}

// ---------------------------------------------------------------------------
// up: conv_transpose 2x2x2 stride-2 VALID (JAX transpose_kernel=False) * mask.
// Exactly one tap per output: k = 1 - (coord & 1) per dim. D,H,W are FINE dims.
// ---------------------------------------------------------------------------
template<int Ci, int Co>
__global__ void __launch_bounds__(TPB) k_up(
    const float* __restrict__ x,    // (D/2,H/2,W/2,Ci)
    const float* __restrict__ wgt,  // (2,2,2,Ci,Co)
    const float* __restrict__ mfine,
    float* __restrict__ out,        // (D,H,W,Co)
    int D, int H, int W)
{
  const int total = D * H * W * Co;
  for (int idx = blockIdx.x * TPB + threadIdx.x; idx < total; idx += gridDim.x * TPB) {
    const int co = idx % Co;
    const int v  = idx / Co;
    const int w = v % W;
    const int h = (v / W) % H;
    const int d = v / (W * H);
    float outv = 0.f;
    if (mfine[v] != 0.f) {
      const int kd = 1 - (d & 1), kh = 1 - (h & 1), kw = 1 - (w & 1);
      const int nv  = ((d >> 1) * (H >> 1) + (h >> 1)) * (W >> 1) + (w >> 1);
      const int tap = (kd * 2 + kh) * 2 + kw;
      const float* __restrict__ wp = wgt + tap * (Ci * Co) + co;
      const float* __restrict__ xp = x + nv * Ci;
      float a0 = 0.f, a1 = 0.f, a2 = 0.f, a3 = 0.f;
      #pragma unroll
      for (int ci = 0; ci < Ci; ci += 4) {
        a0 = fmaf(xp[ci + 0], wp[(ci + 0) * Co], a0);
        a1 = fmaf(xp[ci + 1], wp[(ci + 1) * Co], a1);
        a2 = fmaf(xp[ci + 2], wp[(ci + 2) * Co], a2);
        a3 = fmaf(xp[ci + 3], wp[(ci + 3) * Co], a3);
      }
      outv = (a0 + a1) + (a2 + a3);
    }
    out[idx] = outv;
  }
}

// ---------------------------------------------------------------------------
// head: (c0 @ w_head + b_head) * mask, reshape (NV,5,9), scatter to 5 outputs
// mu_off [0,15NV) | log_sig clip(-5,3) [15NV,30NV) | mu_int | occ | mix (5NV each)
// ---------------------------------------------------------------------------
__global__ void __launch_bounds__(TPB) k_head(
    const float* __restrict__ c0,   // (NV,32)
    const float* __restrict__ wh,   // (32,45)
    const float* __restrict__ bh,   // (45)
    const float* __restrict__ mask,
    float* __restrict__ out, int NV)
{
  const int total = NV * 45;
  for (int idx = blockIdx.x * TPB + threadIdx.x; idx < total; idx += gridDim.x * TPB) {
    const int j = idx % 45;
    const int v = idx / 45;
    float val = 0.f;
    if (mask[v] != 0.f) {
      float a0 = 0.f, a1 = 0.f, a2 = 0.f, a3 = 0.f;
      const float* __restrict__ cp = c0 + v * 32;
      #pragma unroll
      for (int c = 0; c < 32; c += 4) {
        a0 = fmaf(cp[c + 0], wh[(c + 0) * 45 + j], a0);
        a1 = fmaf(cp[c + 1], wh[(c + 1) * 45 + j], a1);
        a2 = fmaf(cp[c + 2], wh[(c + 2) * 45 + j], a2);
        a3 = fmaf(cp[c + 3], wh[(c + 3) * 45 + j], a3);
      }
      val = (a0 + a1) + (a2 + a3) + bh[j];
    }
    const int k = j / 9, r = j % 9;
    const size_t NVs = (size_t)NV;
    if (r < 3)
      out[(size_t)v * 15 + k * 3 + r] = val;
    else if (r < 6)
      out[NVs * 15 + (size_t)v * 15 + k * 3 + (r - 3)] = fminf(fmaxf(val, -5.f), 3.f);
    else if (r == 6)
      out[NVs * 30 + (size_t)v * 5 + k] = val;
    else if (r == 7)
      out[NVs * 35 + (size_t)v * 5 + k] = val;
    else
      out[NVs * 40 + (size_t)v * 5 + k] = val;
  }
}

// ---------------------------------------------------------------------------
extern "C" void kernel_launch(void* const* d_in, const int* in_sizes, int n_in,
                              void* d_out, int out_size, void* d_ws, size_t ws_size,
                              hipStream_t stream)
{
  (void)in_sizes; (void)n_in; (void)out_size;

  const float* x        = (const float*)d_in[0];
  const float* mask0    = (const float*)d_in[1];
  const float* w_enc0   = (const float*)d_in[2];
  const float* bn_enc0  = (const float*)d_in[3];
  const float* w_down0  = (const float*)d_in[4];
  const float* bn_down0 = (const float*)d_in[5];
  const float* w_enc1   = (const float*)d_in[6];
  const float* bn_enc1  = (const float*)d_in[7];
  const float* w_down1  = (const float*)d_in[8];
  const float* bn_down1 = (const float*)d_in[9];
  const float* w_enc2   = (const float*)d_in[10];
  const float* bn_enc2  = (const float*)d_in[11];
  const float* w_down2  = (const float*)d_in[12];
  const float* bn_down2 = (const float*)d_in[13];
  const float* w_bott   = (const float*)d_in[14];
  const float* bn_bott  = (const float*)d_in[15];
  const float* w_up2    = (const float*)d_in[16];
  const float* w_dec2   = (const float*)d_in[17];
  const float* bn_dec2  = (const float*)d_in[18];
  const float* w_up1    = (const float*)d_in[19];
  const float* w_dec1   = (const float*)d_in[20];
  const float* bn_dec1  = (const float*)d_in[21];
  const float* w_up0    = (const float*)d_in[22];
  const float* w_dec0   = (const float*)d_in[23];
  const float* bn_dec0  = (const float*)d_in[24];
  const float* w_head   = (const float*)d_in[25];
  const float* b_head   = (const float*)d_in[26];

  // workspace layout (fp32), with u2 aliasing d1 and u1 aliasing d0 (dead)
  float* ws = (float*)d_ws;
  size_t o = 0;
  auto take = [&](size_t n) { float* p = ws + o; o += n; return p; };
  float* e0 = take(16777216);  // 32*128*128*32
  float* m1 = take(65536);     // 16*64*64
  float* d0 = take(4194304);   // 16*64*64*64     (reused as u1)
  float* e1 = take(4194304);
  float* m2 = take(8192);      // 8*32*32
  float* d1 = take(1048576);   // 8*32*32*128     (reused as u2)
  float* e2 = take(1048576);
  float* m3 = take(1024);      // 4*16*16
  float* d2 = take(262144);    // 4*16*16*256
  float* bb = take(262144);
  float* c2 = take(1048576);
  float* c1 = take(4194304);
  float* u0 = take(16777216);
  float* c0 = take(16777216);
  if (o * sizeof(float) > ws_size) return;  // workspace too small — bail

  float* u2 = d1;  // d1 dead after enc2
  float* u1 = d0;  // d0 dead after enc1

  auto g = [](int total) { return dim3((unsigned)((total + TPB - 1) / TPB)); };

  // encoder
  k_subm<20, 0, 32><<<g(32 * 128 * 128 * 32), TPB, 0, stream>>>(x, nullptr, w_enc0, bn_enc0, mask0, e0, 32, 128, 128);
  k_down<32, 64><<<g(16 * 64 * 64 * 64), TPB, 0, stream>>>(e0, w_down0, bn_down0, mask0, m1, d0, 16, 64, 64);
  k_subm<64, 0, 64><<<g(16 * 64 * 64 * 64), TPB, 0, stream>>>(d0, nullptr, w_enc1, bn_enc1, m1, e1, 16, 64, 64);
  k_down<64, 128><<<g(8 * 32 * 32 * 128), TPB, 0, stream>>>(e1, w_down1, bn_down1, m1, m2, d1, 8, 32, 32);
  k_subm<128, 0, 128><<<g(8 * 32 * 32 * 128), TPB, 0, stream>>>(d1, nullptr, w_enc2, bn_enc2, m2, e2, 8, 32, 32);
  k_down<128, 256><<<g(4 * 16 * 16 * 256), TPB, 0, stream>>>(e2, w_down2, bn_down2, m2, m3, d2, 4, 16, 16);
  // bottleneck
  k_subm<256, 0, 256><<<g(4 * 16 * 16 * 256), TPB, 0, stream>>>(d2, nullptr, w_bott, bn_bott, m3, bb, 4, 16, 16);
  // decoder (concat fused: first input = up, second = skip)
  k_up<256, 128><<<g(8 * 32 * 32 * 128), TPB, 0, stream>>>(bb, w_up2, m2, u2, 8, 32, 32);
  k_subm<128, 128, 128><<<g(8 * 32 * 32 * 128), TPB, 0, stream>>>(u2, e2, w_dec2, bn_dec2, m2, c2, 8, 32, 32);
  k_up<128, 64><<<g(16 * 64 * 64 * 64), TPB, 0, stream>>>(c2, w_up1, m1, u1, 16, 64, 64);
  k_subm<64, 64, 64><<<g(16 * 64 * 64 * 64), TPB, 0, stream>>>(u1, e1, w_dec1, bn_dec1, m1, c1, 16, 64, 64);
  k_up<64, 32><<<g(32 * 128 * 128 * 32), TPB, 0, stream>>>(c1, w_up0, mask0, u0, 32, 128, 128);
  k_subm<32, 32, 32><<<g(32 * 128 * 128 * 32), TPB, 0, stream>>>(u0, e0, w_dec0, bn_dec0, mask0, c0, 32, 128, 128);
  // head
  k_head<<<g(524288 * 45), TPB, 0, stream>>>(c0, w_head, b_head, mask0, (float*)d_out, 524288);
}

// Round 2
// 7201.617 us; speedup vs baseline: 1.3542x; 1.3542x over previous
//
#include <hip/hip_runtime.h>
#include <math.h>

#define TPB 256

// ---------------------------------------------------------------------------
// helpers
// ---------------------------------------------------------------------------
__device__ __forceinline__ float4 ld4(const float* p) { return *(const float4*)p; }

__device__ __forceinline__ void fma4(float s, const float4 w, float4& a) {
  a.x = fmaf(s, w.x, a.x); a.y = fmaf(s, w.y, a.y);
  a.z = fmaf(s, w.z, a.z); a.w = fmaf(s, w.w, a.w);
}

// acc[0..3] over 4 consecutive co; x is one voxel's channel vector (len C, 16B aligned)
// wp points at this tap's weights as float4 rows: wp[ci*TPV + cg]
template<int C, int TPV>
__device__ __forceinline__ void dot4(const float* __restrict__ x,
                                     const float4* __restrict__ wp,
                                     float4& acc0, float4& acc1) {
  const float4* __restrict__ xp = (const float4*)x;
  #pragma unroll 8
  for (int c4 = 0; c4 < C / 4; ++c4) {
    const float4 xv = xp[c4];
    fma4(xv.x, wp[(c4 * 4 + 0) * TPV], acc0);
    fma4(xv.y, wp[(c4 * 4 + 1) * TPV], acc1);
    fma4(xv.z, wp[(c4 * 4 + 2) * TPV], acc0);
    fma4(xv.w, wp[(c4 * 4 + 3) * TPV], acc1);
  }
}

template<int Co>
__device__ __forceinline__ float4 bn_relu(float4 a, const float* __restrict__ bn, int cg) {
  const float4 g = ld4(bn + cg * 4);
  const float4 b = ld4(bn + Co + cg * 4);
  const float4 m = ld4(bn + 2 * Co + cg * 4);
  const float4 v = ld4(bn + 3 * Co + cg * 4);
  float4 r;
  r.x = fmaxf((a.x - m.x) * (g.x * rsqrtf(v.x + 1e-5f)) + b.x, 0.f);
  r.y = fmaxf((a.y - m.y) * (g.y * rsqrtf(v.y + 1e-5f)) + b.y, 0.f);
  r.z = fmaxf((a.z - m.z) * (g.z * rsqrtf(v.z + 1e-5f)) + b.z, 0.f);
  r.w = fmaxf((a.w - m.w) * (g.w * rsqrtf(v.w + 1e-5f)) + b.w, 0.f);
  return r;
}

// ---------------------------------------------------------------------------
// mask pyramid + compaction
// ---------------------------------------------------------------------------
template<int LW, int LH, int D>   // coarse dims (W=1<<LW, H=1<<LH)
__global__ void __launch_bounds__(TPB) k_maskpool(const float* __restrict__ mf,
                                                  float* __restrict__ mc) {
  constexpr int W = 1 << LW, H = 1 << LH;
  constexpr int total = D * H * W;
  const int v = blockIdx.x * TPB + threadIdx.x;
  if (v >= total) return;
  const int w = v & (W - 1), h = (v >> LW) & (H - 1), d = v >> (LW + LH);
  float mp = 0.f;
  #pragma unroll
  for (int dz = 0; dz < 2; ++dz)
    #pragma unroll
    for (int hz = 0; hz < 2; ++hz)
      #pragma unroll
      for (int wz = 0; wz < 2; ++wz)
        mp = fmaxf(mp, mf[((((2*d+dz) << (LH+1)) + (2*h+hz)) << (LW+1)) + (2*w+wz)]);
  mc[v] = mp;
}

__global__ void __launch_bounds__(TPB) k_compact(const float* __restrict__ m, int total,
                                                 int* __restrict__ list, int* __restrict__ cnt) {
  const int v = blockIdx.x * TPB + threadIdx.x;
  if (v < total && m[v] != 0.f) {
    const int p = atomicAdd(cnt, 1);
    list[p] = v;
  }
}

// ---------------------------------------------------------------------------
// subm over active list: 3x3x3 SAME conv (+concat) + BN + ReLU
// thread = (active voxel, group of 4 co). Skips inactive neighbors.
// ---------------------------------------------------------------------------
template<int C1, int C2, int Co, int LW, int LH, int D>
__global__ void __launch_bounds__(TPB) k_subm_a(
    const float* __restrict__ x1, const float* __restrict__ x2,
    const float* __restrict__ wgt, const float* __restrict__ bn,
    const float* __restrict__ mask, const int* __restrict__ list,
    const int* __restrict__ cnt, float* __restrict__ out)
{
  constexpr int Cin = C1 + C2;
  constexpr int TPV = Co / 4;
  constexpr int H = 1 << LH, W = 1 << LW;
  const int n = *cnt;
  const int total = n * TPV;
  for (int i = blockIdx.x * TPB + threadIdx.x; i < total; i += gridDim.x * TPB) {
    const int a = i / TPV;           // TPV is pow2 -> shift
    const int cg = i % TPV;
    const int v = list[a];
    const int w = v & (W - 1), h = (v >> LW) & (H - 1), d = v >> (LW + LH);
    float4 acc0 = make_float4(0.f, 0.f, 0.f, 0.f);
    float4 acc1 = make_float4(0.f, 0.f, 0.f, 0.f);
    for (int kd = 0; kd < 3; ++kd) { const int zd = d + kd - 1; if ((unsigned)zd >= (unsigned)D) continue;
    for (int kh = 0; kh < 3; ++kh) { const int zh = h + kh - 1; if ((unsigned)zh >= (unsigned)H) continue;
    for (int kw = 0; kw < 3; ++kw) { const int zw = w + kw - 1; if ((unsigned)zw >= (unsigned)W) continue;
      const int nv = (((zd << LH) + zh) << LW) + zw;
      if (mask[nv] == 0.f) continue;
      const int tap = (kd * 3 + kh) * 3 + kw;
      const float4* __restrict__ wp = (const float4*)wgt + (size_t)tap * Cin * TPV + cg;
      dot4<C1, TPV>(x1 + (size_t)nv * C1, wp, acc0, acc1);
      if constexpr (C2 > 0)
        dot4<C2, TPV>(x2 + (size_t)nv * C2, wp + C1 * TPV, acc0, acc1);
    }}}
    float4 acc;
    acc.x = acc0.x + acc1.x; acc.y = acc0.y + acc1.y;
    acc.z = acc0.z + acc1.z; acc.w = acc0.w + acc1.w;
    *(float4*)(out + (size_t)v * Co + cg * 4) = bn_relu<Co>(acc, bn, cg);
  }
}

// ---------------------------------------------------------------------------
// down over coarse active list: 2x2x2 stride-2 conv + BN + ReLU, fine-mask skip
// LW,LH,D are COARSE dims
// ---------------------------------------------------------------------------
template<int Ci, int Co, int LW, int LH, int D>
__global__ void __launch_bounds__(TPB) k_down_a(
    const float* __restrict__ x, const float* __restrict__ wgt,
    const float* __restrict__ bn, const float* __restrict__ mfine,
    const int* __restrict__ list, const int* __restrict__ cnt,
    float* __restrict__ out)
{
  constexpr int TPV = Co / 4;
  constexpr int H = 1 << LH, W = 1 << LW;
  const int n = *cnt;
  const int total = n * TPV;
  for (int i = blockIdx.x * TPB + threadIdx.x; i < total; i += gridDim.x * TPB) {
    const int a = i / TPV;
    const int cg = i % TPV;
    const int v = list[a];
    const int w = v & (W - 1), h = (v >> LW) & (H - 1), d = v >> (LW + LH);
    float4 acc0 = make_float4(0.f, 0.f, 0.f, 0.f);
    float4 acc1 = make_float4(0.f, 0.f, 0.f, 0.f);
    #pragma unroll
    for (int kd = 0; kd < 2; ++kd)
      #pragma unroll
      for (int kh = 0; kh < 2; ++kh)
        #pragma unroll
        for (int kw = 0; kw < 2; ++kw) {
          const int nv = ((((2*d+kd) << (LH+1)) + (2*h+kh)) << (LW+1)) + (2*w+kw);
          if (mfine[nv] == 0.f) continue;
          const int tap = (kd * 2 + kh) * 2 + kw;
          const float4* __restrict__ wp = (const float4*)wgt + (size_t)tap * Ci * TPV + cg;
          dot4<Ci, TPV>(x + (size_t)nv * Ci, wp, acc0, acc1);
        }
    float4 acc;
    acc.x = acc0.x + acc1.x; acc.y = acc0.y + acc1.y;
    acc.z = acc0.z + acc1.z; acc.w = acc0.w + acc1.w;
    *(float4*)(out + (size_t)v * Co + cg * 4) = bn_relu<Co>(acc, bn, cg);
  }
}

// ---------------------------------------------------------------------------
// up over FINE active list: 1-tap conv_transpose (k = 1-(coord&1)), no BN.
// Parent coarse voxel is active by maxpool construction.
// LW,LH are FINE dims.
// ---------------------------------------------------------------------------
template<int Ci, int Co, int LW, int LH>
__global__ void __launch_bounds__(TPB) k_up_a(
    const float* __restrict__ x, const float* __restrict__ wgt,
    const int* __restrict__ list, const int* __restrict__ cnt,
    float* __restrict__ out)
{
  constexpr int TPV = Co / 4;
  constexpr int H = 1 << LH, W = 1 << LW;
  const int n = *cnt;
  const int total = n * TPV;
  for (int i = blockIdx.x * TPB + threadIdx.x; i < total; i += gridDim.x * TPB) {
    const int a = i / TPV;
    const int cg = i % TPV;
    const int v = list[a];
    const int w = v & (W - 1), h = (v >> LW) & (H - 1), d = v >> (LW + LH);
    const int kd = 1 - (d & 1), kh = 1 - (h & 1), kw = 1 - (w & 1);
    const int nv = ((((d >> 1) << (LH - 1)) + (h >> 1)) << (LW - 1)) + (w >> 1);
    const int tap = (kd * 2 + kh) * 2 + kw;
    const float4* __restrict__ wp = (const float4*)wgt + (size_t)tap * Ci * TPV + cg;
    float4 acc0 = make_float4(0.f, 0.f, 0.f, 0.f);
    float4 acc1 = make_float4(0.f, 0.f, 0.f, 0.f);
    dot4<Ci, TPV>(x + (size_t)nv * Ci, wp, acc0, acc1);
    float4 acc;
    acc.x = acc0.x + acc1.x; acc.y = acc0.y + acc1.y;
    acc.z = acc0.z + acc1.z; acc.w = acc0.w + acc1.w;
    *(float4*)(out + (size_t)v * Co + cg * 4) = acc;
  }
}

// ---------------------------------------------------------------------------
// head over active list: (c0 @ w + b), scatter into 5 output regions.
// Inactive voxels = 0 via the d_out memset.
// ---------------------------------------------------------------------------
__global__ void __launch_bounds__(TPB) k_head_a(
    const float* __restrict__ c0, const float* __restrict__ wh,
    const float* __restrict__ bh, const int* __restrict__ list,
    const int* __restrict__ cnt, float* __restrict__ out)
{
  __shared__ float sw[32 * 45];
  __shared__ float sb[45];
  for (int t = threadIdx.x; t < 32 * 45; t += TPB) sw[t] = wh[t];
  if (threadIdx.x < 45) sb[threadIdx.x] = bh[threadIdx.x];
  __syncthreads();
  const int n = *cnt;
  const int total = n * 45;
  const size_t NV = 524288;
  for (int i = blockIdx.x * TPB + threadIdx.x; i < total; i += gridDim.x * TPB) {
    const int a = i / 45;
    const int j = i % 45;
    const int v = list[a];
    const float4* __restrict__ cp = (const float4*)(c0 + (size_t)v * 32);
    float a0 = 0.f, a1 = 0.f;
    #pragma unroll
    for (int c4 = 0; c4 < 8; ++c4) {
      const float4 xv = cp[c4];
      a0 = fmaf(xv.x, sw[(c4 * 4 + 0) * 45 + j], a0);
      a1 = fmaf(xv.y, sw[(c4 * 4 + 1) * 45 + j], a1);
      a0 = fmaf(xv.z, sw[(c4 * 4 + 2) * 45 + j], a0);
      a1 = fmaf(xv.w, sw[(c4 * 4 + 3) * 45 + j], a1);
    }
    const float val = a0 + a1 + sb[j];
    const int k = j / 9, r = j % 9;
    if (r < 3)
      out[(size_t)v * 15 + k * 3 + r] = val;
    else if (r < 6)
      out[NV * 15 + (size_t)v * 15 + k * 3 + (r - 3)] = fminf(fmaxf(val, -5.f), 3.f);
    else if (r == 6)
      out[NV * 30 + (size_t)v * 5 + k] = val;
    else if (r == 7)
      out[NV * 35 + (size_t)v * 5 + k] = val;
    else
      out[NV * 40 + (size_t)v * 5 + k] = val;
  }
}

// ---------------------------------------------------------------------------
extern "C" void kernel_launch(void* const* d_in, const int* in_sizes, int n_in,
                              void* d_out, int out_size, void* d_ws, size_t ws_size,
                              hipStream_t stream)
{
  (void)in_sizes; (void)n_in;

  const float* x        = (const float*)d_in[0];
  const float* mask0    = (const float*)d_in[1];
  const float* w_enc0   = (const float*)d_in[2];
  const float* bn_enc0  = (const float*)d_in[3];
  const float* w_down0  = (const float*)d_in[4];
  const float* bn_down0 = (const float*)d_in[5];
  const float* w_enc1   = (const float*)d_in[6];
  const float* bn_enc1  = (const float*)d_in[7];
  const float* w_down1  = (const float*)d_in[8];
  const float* bn_down1 = (const float*)d_in[9];
  const float* w_enc2   = (const float*)d_in[10];
  const float* bn_enc2  = (const float*)d_in[11];
  const float* w_down2  = (const float*)d_in[12];
  const float* bn_down2 = (const float*)d_in[13];
  const float* w_bott   = (const float*)d_in[14];
  const float* bn_bott  = (const float*)d_in[15];
  const float* w_up2    = (const float*)d_in[16];
  const float* w_dec2   = (const float*)d_in[17];
  const float* bn_dec2  = (const float*)d_in[18];
  const float* w_up1    = (const float*)d_in[19];
  const float* w_dec1   = (const float*)d_in[20];
  const float* bn_dec1  = (const float*)d_in[21];
  const float* w_up0    = (const float*)d_in[22];
  const float* w_dec0   = (const float*)d_in[23];
  const float* bn_dec0  = (const float*)d_in[24];
  const float* w_head   = (const float*)d_in[25];
  const float* b_head   = (const float*)d_in[26];

  float* ws = (float*)d_ws;
  size_t o = 0;
  auto take = [&](size_t nf) { float* p = ws + o; o += nf; return p; };

  int*   cnt   = (int*)take(16);          // 4 counters (+pad to 16 floats)
  int*   list0 = (int*)take(524288);
  int*   list1 = (int*)take(65536);
  int*   list2 = (int*)take(8192);
  int*   list3 = (int*)take(1024);
  float* m1    = take(65536);             // 16*64*64
  float* m2    = take(8192);              // 8*32*32
  float* m3    = take(1024);              // 4*16*16
  float* e0 = take(16777216);
  float* d0 = take(4194304);              // reused as u1
  float* e1 = take(4194304);
  float* d1 = take(1048576);              // reused as u2
  float* e2 = take(1048576);
  float* d2 = take(262144);
  float* bb = take(262144);
  float* c2 = take(1048576);
  float* c1 = take(4194304);
  float* u0 = take(16777216);
  float* c0 = take(16777216);
  if (o * sizeof(float) > ws_size) return;
  float* u2 = d1;
  float* u1 = d0;
  int* cnt0 = cnt, *cnt1 = cnt + 1, *cnt2 = cnt + 2, *cnt3 = cnt + 3;

  hipMemsetAsync(cnt, 0, 16, stream);
  hipMemsetAsync(d_out, 0, (size_t)out_size * sizeof(float), stream);

  auto g = [](long long upper) {
    unsigned b = (unsigned)((upper + TPB - 1) / TPB);
    return dim3(b > 4096u ? 4096u : (b ? b : 1u));
  };

  // mask pyramid + compaction (only depend on mask0)
  k_maskpool<6, 6, 16><<<g(65536), TPB, 0, stream>>>(mask0, m1);
  k_maskpool<5, 5, 8><<<g(8192), TPB, 0, stream>>>(m1, m2);
  k_maskpool<4, 4, 4><<<g(1024), TPB, 0, stream>>>(m2, m3);
  k_compact<<<dim3(524288 / TPB), TPB, 0, stream>>>(mask0, 524288, list0, cnt0);
  k_compact<<<dim3(65536 / TPB), TPB, 0, stream>>>(m1, 65536, list1, cnt1);
  k_compact<<<dim3(8192 / TPB), TPB, 0, stream>>>(m2, 8192, list2, cnt2);
  k_compact<<<dim3(1024 / TPB), TPB, 0, stream>>>(m3, 1024, list3, cnt3);

  // encoder
  k_subm_a<20, 0, 32, 7, 7, 32><<<g(524288LL * 8), TPB, 0, stream>>>(x, nullptr, w_enc0, bn_enc0, mask0, list0, cnt0, e0);
  k_down_a<32, 64, 6, 6, 16><<<g(65536LL * 16), TPB, 0, stream>>>(e0, w_down0, bn_down0, mask0, list1, cnt1, d0);
  k_subm_a<64, 0, 64, 6, 6, 16><<<g(65536LL * 16), TPB, 0, stream>>>(d0, nullptr, w_enc1, bn_enc1, m1, list1, cnt1, e1);
  k_down_a<64, 128, 5, 5, 8><<<g(8192LL * 32), TPB, 0, stream>>>(e1, w_down1, bn_down1, m1, list2, cnt2, d1);
  k_subm_a<128, 0, 128, 5, 5, 8><<<g(8192LL * 32), TPB, 0, stream>>>(d1, nullptr, w_enc2, bn_enc2, m2, list2, cnt2, e2);
  k_down_a<128, 256, 4, 4, 4><<<g(1024LL * 64), TPB, 0, stream>>>(e2, w_down2, bn_down2, m2, list3, cnt3, d2);
  // bottleneck
  k_subm_a<256, 0, 256, 4, 4, 4><<<g(1024LL * 64), TPB, 0, stream>>>(d2, nullptr, w_bott, bn_bott, m3, list3, cnt3, bb);
  // decoder
  k_up_a<256, 128, 5, 5><<<g(8192LL * 32), TPB, 0, stream>>>(bb, w_up2, list2, cnt2, u2);
  k_subm_a<128, 128, 128, 5, 5, 8><<<g(8192LL * 32), TPB, 0, stream>>>(u2, e2, w_dec2, bn_dec2, m2, list2, cnt2, c2);
  k_up_a<128, 64, 6, 6><<<g(65536LL * 16), TPB, 0, stream>>>(c2, w_up1, list1, cnt1, u1);
  k_subm_a<64, 64, 64, 6, 6, 16><<<g(65536LL * 16), TPB, 0, stream>>>(u1, e1, w_dec1, bn_dec1, m1, list1, cnt1, c1);
  k_up_a<64, 32, 7, 7><<<g(524288LL * 8), TPB, 0, stream>>>(c1, w_up0, list0, cnt0, u0);
  k_subm_a<32, 32, 32, 7, 7, 32><<<g(524288LL * 8), TPB, 0, stream>>>(u0, e0, w_dec0, bn_dec0, mask0, list0, cnt0, c0);
  // head
  k_head_a<<<g(524288LL * 45), TPB, 0, stream>>>(c0, w_head, b_head, list0, cnt0, (float*)d_out);
}

// Round 3
// 6565.974 us; speedup vs baseline: 1.4853x; 1.0968x over previous
//
#include <hip/hip_runtime.h>
#include <math.h>

#define TPB 256

// ---------------------------------------------------------------------------
// helpers
// ---------------------------------------------------------------------------
__device__ __forceinline__ float4 ld4(const float* p) { return *(const float4*)p; }

__device__ __forceinline__ void fma4(float s, const float4 w, float4& a) {
  a.x = fmaf(s, w.x, a.x); a.y = fmaf(s, w.y, a.y);
  a.z = fmaf(s, w.z, a.z); a.w = fmaf(s, w.w, a.w);
}

template<int C, int TPV>
__device__ __forceinline__ void dot4(const float* __restrict__ x,
                                     const float4* __restrict__ wp,
                                     float4& acc0, float4& acc1) {
  const float4* __restrict__ xp = (const float4*)x;
  #pragma unroll 8
  for (int c4 = 0; c4 < C / 4; ++c4) {
    const float4 xv = xp[c4];
    fma4(xv.x, wp[(c4 * 4 + 0) * TPV], acc0);
    fma4(xv.y, wp[(c4 * 4 + 1) * TPV], acc1);
    fma4(xv.z, wp[(c4 * 4 + 2) * TPV], acc0);
    fma4(xv.w, wp[(c4 * 4 + 3) * TPV], acc1);
  }
}

template<int Co>
__device__ __forceinline__ float4 bn_relu(float4 a, const float* __restrict__ bn, int cg) {
  const float4 g = ld4(bn + cg * 4);
  const float4 b = ld4(bn + Co + cg * 4);
  const float4 m = ld4(bn + 2 * Co + cg * 4);
  const float4 v = ld4(bn + 3 * Co + cg * 4);
  float4 r;
  r.x = fmaxf((a.x - m.x) * (g.x * rsqrtf(v.x + 1e-5f)) + b.x, 0.f);
  r.y = fmaxf((a.y - m.y) * (g.y * rsqrtf(v.y + 1e-5f)) + b.y, 0.f);
  r.z = fmaxf((a.z - m.z) * (g.z * rsqrtf(v.z + 1e-5f)) + b.z, 0.f);
  r.w = fmaxf((a.w - m.w) * (g.w * rsqrtf(v.w + 1e-5f)) + b.w, 0.f);
  return r;
}

// ---------------------------------------------------------------------------
// mask pyramid
// ---------------------------------------------------------------------------
template<int LW, int LH, int D>   // coarse dims
__global__ void __launch_bounds__(TPB) k_maskpool(const float* __restrict__ mf,
                                                  float* __restrict__ mc) {
  constexpr int W = 1 << LW, H = 1 << LH;
  constexpr int total = D * H * W;
  const int v = blockIdx.x * TPB + threadIdx.x;
  if (v >= total) return;
  const int w = v & (W - 1), h = (v >> LW) & (H - 1), d = v >> (LW + LH);
  float mp = 0.f;
  #pragma unroll
  for (int dz = 0; dz < 2; ++dz)
    #pragma unroll
    for (int hz = 0; hz < 2; ++hz)
      #pragma unroll
      for (int wz = 0; wz < 2; ++wz)
        mp = fmaxf(mp, mf[((((2*d+dz) << (LH+1)) + (2*h+hz)) << (LW+1)) + (2*w+wz)]);
  mc[v] = mp;
}

// ---------------------------------------------------------------------------
// deterministic ordered compaction: count -> scan -> fill  (list in linear order)
// ---------------------------------------------------------------------------
__global__ void __launch_bounds__(TPB) k_count(const float* __restrict__ m, int total,
                                               int* __restrict__ bcount) {
  const int v = blockIdx.x * TPB + threadIdx.x;
  const bool act = (v < total) && (m[v] != 0.f);
  const unsigned long long b = __ballot(act);
  __shared__ int wc[TPB / 64];
  const int wid = threadIdx.x >> 6;
  if ((threadIdx.x & 63) == 0) wc[wid] = __popcll(b);
  __syncthreads();
  if (threadIdx.x == 0) bcount[blockIdx.x] = wc[0] + wc[1] + wc[2] + wc[3];
}

// single block, 1024 threads, nb <= 2048
__global__ void __launch_bounds__(1024) k_scan(const int* __restrict__ bc, int nb,
                                               int* __restrict__ boff, int* __restrict__ total) {
  __shared__ int part[1024];
  const int t = threadIdx.x;
  const int a0 = (2 * t     < nb) ? bc[2 * t]     : 0;
  const int a1 = (2 * t + 1 < nb) ? bc[2 * t + 1] : 0;
  part[t] = a0 + a1;
  __syncthreads();
  for (int off = 1; off < 1024; off <<= 1) {
    const int tmp = (t >= off) ? part[t - off] : 0;
    __syncthreads();
    part[t] += tmp;
    __syncthreads();
  }
  const int excl = (t == 0) ? 0 : part[t - 1];
  if (2 * t     < nb) boff[2 * t]     = excl;
  if (2 * t + 1 < nb) boff[2 * t + 1] = excl + a0;
  if (t == 1023) *total = part[1023];
}

__global__ void __launch_bounds__(TPB) k_fill(const float* __restrict__ m, int total,
                                              const int* __restrict__ boff,
                                              int* __restrict__ list) {
  const int v = blockIdx.x * TPB + threadIdx.x;
  const bool act = (v < total) && (m[v] != 0.f);
  const unsigned long long b = __ballot(act);
  const int wid = threadIdx.x >> 6, lane = threadIdx.x & 63;
  __shared__ int wc[TPB / 64];
  __shared__ int wbase[TPB / 64];
  if (lane == 0) wc[wid] = __popcll(b);
  __syncthreads();
  if (threadIdx.x == 0) {
    int s = boff[blockIdx.x];
    #pragma unroll
    for (int i = 0; i < TPB / 64; ++i) { wbase[i] = s; s += wc[i]; }
  }
  __syncthreads();
  if (act) {
    const int rank = __popcll(b & ((1ull << lane) - 1ull));
    list[wbase[wid] + rank] = v;
  }
}

// ---------------------------------------------------------------------------
// subm over active list: 3x3x3 SAME conv (+concat) + BN + ReLU
// ---------------------------------------------------------------------------
template<int C1, int C2, int Co, int LW, int LH, int D>
__global__ void __launch_bounds__(TPB) k_subm_a(
    const float* __restrict__ x1, const float* __restrict__ x2,
    const float* __restrict__ wgt, const float* __restrict__ bn,
    const float* __restrict__ mask, const int* __restrict__ list,
    const int* __restrict__ cnt, float* __restrict__ out)
{
  constexpr int Cin = C1 + C2;
  constexpr int TPV = Co / 4;
  constexpr int H = 1 << LH, W = 1 << LW;
  const int n = *cnt;
  const int total = n * TPV;
  for (int i = blockIdx.x * TPB + threadIdx.x; i < total; i += gridDim.x * TPB) {
    const int a = i / TPV;
    const int cg = i % TPV;
    const int v = list[a];
    const int w = v & (W - 1), h = (v >> LW) & (H - 1), d = v >> (LW + LH);
    float4 acc0 = make_float4(0.f, 0.f, 0.f, 0.f);
    float4 acc1 = make_float4(0.f, 0.f, 0.f, 0.f);
    for (int kd = 0; kd < 3; ++kd) { const int zd = d + kd - 1; if ((unsigned)zd >= (unsigned)D) continue;
    for (int kh = 0; kh < 3; ++kh) { const int zh = h + kh - 1; if ((unsigned)zh >= (unsigned)H) continue;
    for (int kw = 0; kw < 3; ++kw) { const int zw = w + kw - 1; if ((unsigned)zw >= (unsigned)W) continue;
      const int nv = (((zd << LH) + zh) << LW) + zw;
      if (mask[nv] == 0.f) continue;
      const int tap = (kd * 3 + kh) * 3 + kw;
      const float4* __restrict__ wp = (const float4*)wgt + (size_t)tap * Cin * TPV + cg;
      dot4<C1, TPV>(x1 + (size_t)nv * C1, wp, acc0, acc1);
      if constexpr (C2 > 0)
        dot4<C2, TPV>(x2 + (size_t)nv * C2, wp + C1 * TPV, acc0, acc1);
    }}}
    float4 acc;
    acc.x = acc0.x + acc1.x; acc.y = acc0.y + acc1.y;
    acc.z = acc0.z + acc1.z; acc.w = acc0.w + acc1.w;
    *(float4*)(out + (size_t)v * Co + cg * 4) = bn_relu<Co>(acc, bn, cg);
  }
}

// ---------------------------------------------------------------------------
// down over coarse active list
// ---------------------------------------------------------------------------
template<int Ci, int Co, int LW, int LH, int D>
__global__ void __launch_bounds__(TPB) k_down_a(
    const float* __restrict__ x, const float* __restrict__ wgt,
    const float* __restrict__ bn, const float* __restrict__ mfine,
    const int* __restrict__ list, const int* __restrict__ cnt,
    float* __restrict__ out)
{
  constexpr int TPV = Co / 4;
  constexpr int H = 1 << LH, W = 1 << LW;
  const int n = *cnt;
  const int total = n * TPV;
  for (int i = blockIdx.x * TPB + threadIdx.x; i < total; i += gridDim.x * TPB) {
    const int a = i / TPV;
    const int cg = i % TPV;
    const int v = list[a];
    const int w = v & (W - 1), h = (v >> LW) & (H - 1), d = v >> (LW + LH);
    float4 acc0 = make_float4(0.f, 0.f, 0.f, 0.f);
    float4 acc1 = make_float4(0.f, 0.f, 0.f, 0.f);
    #pragma unroll
    for (int kd = 0; kd < 2; ++kd)
      #pragma unroll
      for (int kh = 0; kh < 2; ++kh)
        #pragma unroll
        for (int kw = 0; kw < 2; ++kw) {
          const int nv = ((((2*d+kd) << (LH+1)) + (2*h+kh)) << (LW+1)) + (2*w+kw);
          if (mfine[nv] == 0.f) continue;
          const int tap = (kd * 2 + kh) * 2 + kw;
          const float4* __restrict__ wp = (const float4*)wgt + (size_t)tap * Ci * TPV + cg;
          dot4<Ci, TPV>(x + (size_t)nv * Ci, wp, acc0, acc1);
        }
    float4 acc;
    acc.x = acc0.x + acc1.x; acc.y = acc0.y + acc1.y;
    acc.z = acc0.z + acc1.z; acc.w = acc0.w + acc1.w;
    *(float4*)(out + (size_t)v * Co + cg * 4) = bn_relu<Co>(acc, bn, cg);
  }
}

// ---------------------------------------------------------------------------
// up over FINE active list: 1-tap conv_transpose
// ---------------------------------------------------------------------------
template<int Ci, int Co, int LW, int LH>
__global__ void __launch_bounds__(TPB) k_up_a(
    const float* __restrict__ x, const float* __restrict__ wgt,
    const int* __restrict__ list, const int* __restrict__ cnt,
    float* __restrict__ out)
{
  constexpr int TPV = Co / 4;
  constexpr int H = 1 << LH, W = 1 << LW;
  const int n = *cnt;
  const int total = n * TPV;
  for (int i = blockIdx.x * TPB + threadIdx.x; i < total; i += gridDim.x * TPB) {
    const int a = i / TPV;
    const int cg = i % TPV;
    const int v = list[a];
    const int w = v & (W - 1), h = (v >> LW) & (H - 1), d = v >> (LW + LH);
    const int kd = 1 - (d & 1), kh = 1 - (h & 1), kw = 1 - (w & 1);
    const int nv = ((((d >> 1) << (LH - 1)) + (h >> 1)) << (LW - 1)) + (w >> 1);
    const int tap = (kd * 2 + kh) * 2 + kw;
    const float4* __restrict__ wp = (const float4*)wgt + (size_t)tap * Ci * TPV + cg;
    float4 acc0 = make_float4(0.f, 0.f, 0.f, 0.f);
    float4 acc1 = make_float4(0.f, 0.f, 0.f, 0.f);
    dot4<Ci, TPV>(x + (size_t)nv * Ci, wp, acc0, acc1);
    float4 acc;
    acc.x = acc0.x + acc1.x; acc.y = acc0.y + acc1.y;
    acc.z = acc0.z + acc1.z; acc.w = acc0.w + acc1.w;
    *(float4*)(out + (size_t)v * Co + cg * 4) = acc;
  }
}

// ---------------------------------------------------------------------------
// head over active list
// ---------------------------------------------------------------------------
__global__ void __launch_bounds__(TPB) k_head_a(
    const float* __restrict__ c0, const float* __restrict__ wh,
    const float* __restrict__ bh, const int* __restrict__ list,
    const int* __restrict__ cnt, float* __restrict__ out)
{
  __shared__ float sw[32 * 45];
  __shared__ float sb[45];
  for (int t = threadIdx.x; t < 32 * 45; t += TPB) sw[t] = wh[t];
  if (threadIdx.x < 45) sb[threadIdx.x] = bh[threadIdx.x];
  __syncthreads();
  const int n = *cnt;
  const int total = n * 45;
  const size_t NV = 524288;
  for (int i = blockIdx.x * TPB + threadIdx.x; i < total; i += gridDim.x * TPB) {
    const int a = i / 45;
    const int j = i % 45;
    const int v = list[a];
    const float4* __restrict__ cp = (const float4*)(c0 + (size_t)v * 32);
    float a0 = 0.f, a1 = 0.f;
    #pragma unroll
    for (int c4 = 0; c4 < 8; ++c4) {
      const float4 xv = cp[c4];
      a0 = fmaf(xv.x, sw[(c4 * 4 + 0) * 45 + j], a0);
      a1 = fmaf(xv.y, sw[(c4 * 4 + 1) * 45 + j], a1);
      a0 = fmaf(xv.z, sw[(c4 * 4 + 2) * 45 + j], a0);
      a1 = fmaf(xv.w, sw[(c4 * 4 + 3) * 45 + j], a1);
    }
    const float val = a0 + a1 + sb[j];
    const int k = j / 9, r = j % 9;
    if (r < 3)
      out[(size_t)v * 15 + k * 3 + r] = val;
    else if (r < 6)
      out[NV * 15 + (size_t)v * 15 + k * 3 + (r - 3)] = fminf(fmaxf(val, -5.f), 3.f);
    else if (r == 6)
      out[NV * 30 + (size_t)v * 5 + k] = val;
    else if (r == 7)
      out[NV * 35 + (size_t)v * 5 + k] = val;
    else
      out[NV * 40 + (size_t)v * 5 + k] = val;
  }
}

// ---------------------------------------------------------------------------
extern "C" void kernel_launch(void* const* d_in, const int* in_sizes, int n_in,
                              void* d_out, int out_size, void* d_ws, size_t ws_size,
                              hipStream_t stream)
{
  (void)in_sizes; (void)n_in;

  const float* x        = (const float*)d_in[0];
  const float* mask0    = (const float*)d_in[1];
  const float* w_enc0   = (const float*)d_in[2];
  const float* bn_enc0  = (const float*)d_in[3];
  const float* w_down0  = (const float*)d_in[4];
  const float* bn_down0 = (const float*)d_in[5];
  const float* w_enc1   = (const float*)d_in[6];
  const float* bn_enc1  = (const float*)d_in[7];
  const float* w_down1  = (const float*)d_in[8];
  const float* bn_down1 = (const float*)d_in[9];
  const float* w_enc2   = (const float*)d_in[10];
  const float* bn_enc2  = (const float*)d_in[11];
  const float* w_down2  = (const float*)d_in[12];
  const float* bn_down2 = (const float*)d_in[13];
  const float* w_bott   = (const float*)d_in[14];
  const float* bn_bott  = (const float*)d_in[15];
  const float* w_up2    = (const float*)d_in[16];
  const float* w_dec2   = (const float*)d_in[17];
  const float* bn_dec2  = (const float*)d_in[18];
  const float* w_up1    = (const float*)d_in[19];
  const float* w_dec1   = (const float*)d_in[20];
  const float* bn_dec1  = (const float*)d_in[21];
  const float* w_up0    = (const float*)d_in[22];
  const float* w_dec0   = (const float*)d_in[23];
  const float* bn_dec0  = (const float*)d_in[24];
  const float* w_head   = (const float*)d_in[25];
  const float* b_head   = (const float*)d_in[26];

  float* ws = (float*)d_ws;
  size_t o = 0;
  auto take = [&](size_t nf) { float* p = ws + o; o += nf; return p; };

  int*   cnt   = (int*)take(16);          // 4 totals
  int*   bcnt  = (int*)take(2048);        // per-block counts (max level 0)
  int*   boff  = (int*)take(2048);        // per-block offsets
  int*   list0 = (int*)take(524288);
  int*   list1 = (int*)take(65536);
  int*   list2 = (int*)take(8192);
  int*   list3 = (int*)take(1024);
  float* m1    = take(65536);
  float* m2    = take(8192);
  float* m3    = take(1024);
  float* e0 = take(16777216);
  float* d0 = take(4194304);              // reused as u1
  float* e1 = take(4194304);
  float* d1 = take(1048576);              // reused as u2
  float* e2 = take(1048576);
  float* d2 = take(262144);
  float* bb = take(262144);
  float* c2 = take(1048576);
  float* c1 = take(4194304);
  float* u0 = take(16777216);
  float* c0 = take(16777216);
  if (o * sizeof(float) > ws_size) return;
  float* u2 = d1;
  float* u1 = d0;
  int* cnt0 = cnt, *cnt1 = cnt + 1, *cnt2 = cnt + 2, *cnt3 = cnt + 3;

  hipMemsetAsync(d_out, 0, (size_t)out_size * sizeof(float), stream);

  auto g = [](long long upper) {
    unsigned b = (unsigned)((upper + TPB - 1) / TPB);
    return dim3(b > 4096u ? 4096u : (b ? b : 1u));
  };

  // mask pyramid
  k_maskpool<6, 6, 16><<<g(65536), TPB, 0, stream>>>(mask0, m1);
  k_maskpool<5, 5, 8><<<g(8192), TPB, 0, stream>>>(m1, m2);
  k_maskpool<4, 4, 4><<<g(1024), TPB, 0, stream>>>(m2, m3);

  // deterministic ordered compaction per level (count -> scan -> fill)
  auto compact = [&](const float* m, int total, int* list, int* cptr) {
    const int nb = total / TPB;
    k_count<<<dim3((unsigned)nb), TPB, 0, stream>>>(m, total, bcnt);
    k_scan<<<dim3(1), 1024, 0, stream>>>(bcnt, nb, boff, cptr);
    k_fill<<<dim3((unsigned)nb), TPB, 0, stream>>>(m, total, boff, list);
  };
  compact(mask0, 524288, list0, cnt0);
  compact(m1,     65536, list1, cnt1);
  compact(m2,      8192, list2, cnt2);
  compact(m3,      1024, list3, cnt3);

  // encoder
  k_subm_a<20, 0, 32, 7, 7, 32><<<g(524288LL * 8), TPB, 0, stream>>>(x, nullptr, w_enc0, bn_enc0, mask0, list0, cnt0, e0);
  k_down_a<32, 64, 6, 6, 16><<<g(65536LL * 16), TPB, 0, stream>>>(e0, w_down0, bn_down0, mask0, list1, cnt1, d0);
  k_subm_a<64, 0, 64, 6, 6, 16><<<g(65536LL * 16), TPB, 0, stream>>>(d0, nullptr, w_enc1, bn_enc1, m1, list1, cnt1, e1);
  k_down_a<64, 128, 5, 5, 8><<<g(8192LL * 32), TPB, 0, stream>>>(e1, w_down1, bn_down1, m1, list2, cnt2, d1);
  k_subm_a<128, 0, 128, 5, 5, 8><<<g(8192LL * 32), TPB, 0, stream>>>(d1, nullptr, w_enc2, bn_enc2, m2, list2, cnt2, e2);
  k_down_a<128, 256, 4, 4, 4><<<g(1024LL * 64), TPB, 0, stream>>>(e2, w_down2, bn_down2, m2, list3, cnt3, d2);
  // bottleneck
  k_subm_a<256, 0, 256, 4, 4, 4><<<g(1024LL * 64), TPB, 0, stream>>>(d2, nullptr, w_bott, bn_bott, m3, list3, cnt3, bb);
  // decoder
  k_up_a<256, 128, 5, 5><<<g(8192LL * 32), TPB, 0, stream>>>(bb, w_up2, list2, cnt2, u2);
  k_subm_a<128, 128, 128, 5, 5, 8><<<g(8192LL * 32), TPB, 0, stream>>>(u2, e2, w_dec2, bn_dec2, m2, list2, cnt2, c2);
  k_up_a<128, 64, 6, 6><<<g(65536LL * 16), TPB, 0, stream>>>(c2, w_up1, list1, cnt1, u1);
  k_subm_a<64, 64, 64, 6, 6, 16><<<g(65536LL * 16), TPB, 0, stream>>>(u1, e1, w_dec1, bn_dec1, m1, list1, cnt1, c1);
  k_up_a<64, 32, 7, 7><<<g(524288LL * 8), TPB, 0, stream>>>(c1, w_up0, list0, cnt0, u0);
  k_subm_a<32, 32, 32, 7, 7, 32><<<g(524288LL * 8), TPB, 0, stream>>>(u0, e0, w_dec0, bn_dec0, mask0, list0, cnt0, c0);
  // head
  k_head_a<<<g(524288LL * 45), TPB, 0, stream>>>(c0, w_head, b_head, list0, cnt0, (float*)d_out);
}